// Round 7
// baseline (829.360 us; speedup 1.0000x reference)
//
#include <hip/hip_runtime.h>
#include <hip/hip_fp16.h>

#define NCH 128
#define NSL 8            // channel slices (16 ch each), pinned to XCD via blockIdx%8
#define G_NODES 256      // nodes per bucket
#define EPB 4096         // edges per block, pass A
#define RCAP 4864        // per-bucket edge capacity
#define MAXNB 512        // max buckets (N <= 128k)
#define KST 40           // LDS row stride in 2B elems (80B -> 2-way conflict = free)

typedef __attribute__((ext_vector_type(8))) short short8;
typedef _Float16 half8 __attribute__((ext_vector_type(8)));
typedef __attribute__((ext_vector_type(4))) float floatx4;

static inline size_t align256(size_t x){ return (x + 255) & ~(size_t)255; }

// ---------------- Pass A: LDS-binned edge bucketing ----------------
__global__ __launch_bounds__(256) void binA_kernel(
    const int* __restrict__ row, const int* __restrict__ col,
    int* __restrict__ gcur, unsigned* __restrict__ bucketed, int E, int NB){
  __shared__ int cnt[MAXNB];
  __shared__ int lbase[MAXNB];
  __shared__ int gbase[MAXNB];
  __shared__ unsigned sorted[EPB];
  __shared__ unsigned short binOf[EPB];
  __shared__ int sh[256];
  __shared__ int carry;
  int t = threadIdx.x;
  int e0 = blockIdx.x * EPB;
  int ecnt = min(EPB, E - e0);
  for (int i = t; i < NB; i += 256) cnt[i] = 0;
  if (t == 0) carry = 0;
  __syncthreads();
  unsigned rec[16]; int bn[16]; int rk[16];
  #pragma unroll
  for (int i = 0; i < 16; i++){
    int e = e0 + i * 256 + t;
    if (e < E){
      int r = row[e], c = col[e];
      bn[i]  = c >> 8;
      rec[i] = (unsigned)r | ((unsigned)(c & 255) << 17);
      rk[i]  = atomicAdd(&cnt[bn[i]], 1);
    } else bn[i] = -1;
  }
  __syncthreads();
  for (int start = 0; start < NB; start += 256){
    int i = start + t;
    int v = (i < NB) ? cnt[i] : 0;
    sh[t] = v; __syncthreads();
    for (int off = 1; off < 256; off <<= 1){
      int val = (t >= off) ? sh[t - off] : 0;
      __syncthreads(); sh[t] += val; __syncthreads();
    }
    if (i < NB) lbase[i] = sh[t] - v + carry;
    __syncthreads();
    if (t == 255) carry += sh[255];
    __syncthreads();
  }
  for (int i = t; i < NB; i += 256){
    int c = cnt[i];
    gbase[i] = (c > 0) ? atomicAdd(&gcur[i], c) : 0;
  }
  __syncthreads();
  #pragma unroll
  for (int i = 0; i < 16; i++){
    if (bn[i] >= 0){
      int pos = lbase[bn[i]] + rk[i];
      sorted[pos] = rec[i];
      binOf[pos]  = (unsigned short)bn[i];
    }
  }
  __syncthreads();
  for (int idx = t; idx < ecnt; idx += 256){
    int b = binOf[idx];
    int gpos = gbase[b] + (idx - lbase[b]);
    if (gpos < RCAP) bucketed[(size_t)b * RCAP + gpos] = sorted[idx];
  }
}

__global__ void bscan_kernel(const int* __restrict__ gcur, int* __restrict__ bbase, int nb){
  __shared__ int sh[256];
  __shared__ int carry;
  int t = threadIdx.x;
  if (t == 0) carry = 0;
  __syncthreads();
  for (int start = 0; start < nb; start += 256){
    int i = start + t;
    int v = (i < nb) ? min(gcur[i], RCAP) : 0;
    int orig = v;
    sh[t] = v; __syncthreads();
    for (int off = 1; off < 256; off <<= 1){
      int val = (t >= off) ? sh[t - off] : 0;
      __syncthreads(); sh[t] += val; __syncthreads();
    }
    if (i < nb) bbase[i] = sh[t] - orig + carry;
    __syncthreads();
    if (t == 255) carry += sh[255];
    __syncthreads();
  }
}

// ---------------- Pass B: per-bucket LDS counting sort -> final CSR ----------------
__global__ __launch_bounds__(256) void binB_kernel(
    const unsigned* __restrict__ bucketed, const int* __restrict__ gcur,
    const int* __restrict__ bbase, int* __restrict__ rows_sorted,
    int* __restrict__ offs, int* __restrict__ counts, float* __restrict__ dinv, int N){
  __shared__ unsigned ledge[RCAP];
  __shared__ int cnt[G_NODES];
  __shared__ int cnt2[G_NODES];
  __shared__ int lex[G_NODES];
  __shared__ int sh[256];
  int b = blockIdx.x, t = threadIdx.x;
  int size = min(gcur[b], RCAP);
  int base = bbase[b];
  int n0 = b * G_NODES;
  cnt[t] = 0; cnt2[t] = 0;
  __syncthreads();
  for (int i = t; i < size; i += 256){
    unsigned v = bucketed[(size_t)b * RCAP + i];
    ledge[i] = v;
    atomicAdd(&cnt[v >> 17], 1);
  }
  __syncthreads();
  {
    int v = cnt[t];
    sh[t] = v; __syncthreads();
    for (int off = 1; off < 256; off <<= 1){
      int val = (t >= off) ? sh[t - off] : 0;
      __syncthreads(); sh[t] += val; __syncthreads();
    }
    lex[t] = sh[t] - v;
    int n = n0 + t;
    if (n < N){
      counts[n] = v;
      offs[n]   = base + sh[t] - v;
      dinv[n]   = rsqrtf((float)v + 1.0f);
    }
  }
  __syncthreads();
  for (int i = t; i < size; i += 256){
    unsigned v = ledge[i];
    int node = v >> 17;
    int pos = lex[node] + atomicAdd(&cnt2[node], 1);
    rows_sorted[base + pos] = (int)(v & 0x1FFFFu);
  }
}

// ---------------- W prep ----------------
__global__ void wprep_kernel(const float* __restrict__ W1, const float* __restrict__ W2,
                             const float* __restrict__ Wm1, short* __restrict__ planes){
  int mat = blockIdx.x >> 6;
  int idx = ((blockIdx.x & 63) << 8) + threadIdx.x;   // 0..16383
  int k = idx >> 7, n = idx & 127;
  const float* src = (mat == 0) ? W1 : (mat == 1) ? W2 : (mat == 2) ? Wm1 : (Wm1 + 16384);
  float x = src[idx];
  short hs, ls;
  if (mat == 0){
    unsigned u = __float_as_uint(x);
    hs = (short)(u >> 16);
    float hf = __uint_as_float(u & 0xFFFF0000u);
    ls = (short)(__float_as_uint(x - hf) >> 16);
  } else {
    __half h = __float2half(x);
    __half l = __float2half(x - __half2float(h));
    hs = __half_as_short(h); ls = __half_as_short(l);
  }
  planes[(size_t)(2 * mat) * 16384 + n * 128 + k]     = hs;
  planes[(size_t)(2 * mat + 1) * 16384 + n * 128 + k] = ls;
}

// Sliced layout helper: element (slice, node, c) at buf[(slice*N + node)*16 + c]
// ---------------- GEMM (fp32 input): 3-MFMA bf16 split, sliced fp16 out ----------------
__global__ __launch_bounds__(512, 4) void gemm_f32(
    const float* __restrict__ X, const short* __restrict__ Whi_,
    const short* __restrict__ Wlo_, const float* __restrict__ scale,
    __half* __restrict__ O, int nrows, int do_scale){
  __shared__ short Xhi[128 * KST];
  __shared__ short Xlo[128 * KST];
  __shared__ short Whi[128 * KST];
  __shared__ short Wlo[128 * KST];
  int t = threadIdx.x;
  int w = t >> 6, lane = t & 63;
  int m = lane & 15, q = lane >> 4;
  int row0 = blockIdx.x * 128;
  int N = nrows;
  floatx4 acc[8];
  #pragma unroll
  for (int ct = 0; ct < 8; ct++) acc[ct] = (floatx4)0.f;

  for (int kc = 0; kc < 4; kc++){
    int k0 = kc * 32;
    __syncthreads();
    #pragma unroll
    for (int qq = 0; qq < 2; qq++){
      int f = t + 512 * qq;
      int r = f >> 3, kq = f & 7;
      int gr = row0 + r;
      int grc = (gr < nrows) ? gr : 0;
      float4 v = *(const float4*)(X + (size_t)grc * NCH + k0 + kq * 4);
      short h[4], l[4];
      float vv[4] = {v.x, v.y, v.z, v.w};
      #pragma unroll
      for (int j = 0; j < 4; j++){
        unsigned u = __float_as_uint(vv[j]);
        h[j] = (short)(u >> 16);
        float hf = __uint_as_float(u & 0xFFFF0000u);
        l[j] = (short)(__float_as_uint(vv[j] - hf) >> 16);
      }
      *(uint2*)(Xhi + r * KST + kq * 4) = *(uint2*)h;
      *(uint2*)(Xlo + r * KST + kq * 4) = *(uint2*)l;
    }
    {
      int n = t >> 2, kq = t & 3;
      *(uint4*)(Whi + n * KST + kq * 8) = *(const uint4*)(Whi_ + n * NCH + k0 + kq * 8);
      *(uint4*)(Wlo + n * KST + kq * 8) = *(const uint4*)(Wlo_ + n * NCH + k0 + kq * 8);
    }
    __syncthreads();
    short8 a_hi = *(const short8*)(Xhi + (w * 16 + m) * KST + q * 8);
    short8 a_lo = *(const short8*)(Xlo + (w * 16 + m) * KST + q * 8);
    #pragma unroll
    for (int ct = 0; ct < 8; ct++){
      short8 b_hi = *(const short8*)(Whi + (ct * 16 + m) * KST + q * 8);
      short8 b_lo = *(const short8*)(Wlo + (ct * 16 + m) * KST + q * 8);
      acc[ct] = __builtin_amdgcn_mfma_f32_16x16x32_bf16(a_hi, b_hi, acc[ct], 0, 0, 0);
      acc[ct] = __builtin_amdgcn_mfma_f32_16x16x32_bf16(a_lo, b_hi, acc[ct], 0, 0, 0);
      acc[ct] = __builtin_amdgcn_mfma_f32_16x16x32_bf16(a_hi, b_lo, acc[ct], 0, 0, 0);
    }
  }
  #pragma unroll
  for (int r = 0; r < 4; r++){
    int grow = row0 + w * 16 + q * 4 + r;
    if (grow < nrows){
      float sc = do_scale ? scale[grow] : 1.0f;
      #pragma unroll
      for (int ct = 0; ct < 8; ct++)
        O[((size_t)ct * N + grow) * 16 + m] = __float2half(acc[ct][r] * sc);
    }
  }
}

// ---------------- GEMM (fp16 sliced input): 2-MFMA f16, NCT col-tiles ----------------
template<int NCT>
__global__ __launch_bounds__(512, 4) void gemm_f16k(
    const __half* __restrict__ X,
    const short* __restrict__ Whi0, const short* __restrict__ Wlo0,
    const short* __restrict__ Whi1, const short* __restrict__ Wlo1,
    const float* __restrict__ scale,
    __half* __restrict__ O0, __half* __restrict__ O1, int nrows, int do_scale){
  __shared__ short Xs[128 * KST];
  __shared__ short Whs[NCT * 16 * KST];
  __shared__ short Wls[NCT * 16 * KST];
  int t = threadIdx.x;
  int w = t >> 6, lane = t & 63;
  int m = lane & 15, q = lane >> 4;
  int row0 = blockIdx.x * 128;
  int N = nrows;
  floatx4 acc[NCT];
  #pragma unroll
  for (int ct = 0; ct < NCT; ct++) acc[ct] = (floatx4)0.f;

  for (int kc = 0; kc < 4; kc++){
    int k0 = kc * 32;
    __syncthreads();
    {
      int r = t >> 2, kq = t & 3;      // 8 ch starting at k0+kq*8
      int gr = row0 + r;
      int grc = (gr < nrows) ? gr : 0;
      int ch0 = k0 + kq * 8;
      int sl = ch0 >> 4, within = ch0 & 15;
      *(uint4*)(Xs + r * KST + kq * 8) =
        *(const uint4*)(X + ((size_t)sl * N + grc) * 16 + within);
    }
    #pragma unroll
    for (int i = t; i < NCT * 16 * 4; i += 512){
      int n = i >> 2, kq = i & 3;
      const short* sh = (n < 128) ? (Whi0 + n * NCH) : (Whi1 + (n - 128) * NCH);
      const short* sl = (n < 128) ? (Wlo0 + n * NCH) : (Wlo1 + (n - 128) * NCH);
      *(uint4*)(Whs + n * KST + kq * 8) = *(const uint4*)(sh + k0 + kq * 8);
      *(uint4*)(Wls + n * KST + kq * 8) = *(const uint4*)(sl + k0 + kq * 8);
    }
    __syncthreads();
    half8 a = *(const half8*)(Xs + (w * 16 + m) * KST + q * 8);
    #pragma unroll
    for (int ct = 0; ct < NCT; ct++){
      half8 bh = *(const half8*)(Whs + (ct * 16 + m) * KST + q * 8);
      half8 bl = *(const half8*)(Wls + (ct * 16 + m) * KST + q * 8);
      acc[ct] = __builtin_amdgcn_mfma_f32_16x16x32_f16(a, bh, acc[ct], 0, 0, 0);
      acc[ct] = __builtin_amdgcn_mfma_f32_16x16x32_f16(a, bl, acc[ct], 0, 0, 0);
    }
  }
  #pragma unroll
  for (int r = 0; r < 4; r++){
    int grow = row0 + w * 16 + q * 4 + r;
    if (grow < nrows){
      float sc = do_scale ? scale[grow] : 1.0f;
      #pragma unroll
      for (int ct = 0; ct < NCT; ct++){
        __half val = __float2half(acc[ct][r] * sc);
        if (ct < 8) O0[((size_t)ct * N + grow) * 16 + m] = val;
        else        O1[((size_t)(ct - 8) * N + grow) * 16 + m] = val;
      }
    }
  }
}

// ---------------- agg: wave per (node, slice); slice = blockIdx%8 -> XCD-pinned ----------------
// lane = (g,h): g=lane>>3 edge subgroup (8 in flight), h=lane&7 half2 chunk of 16-ch slice.
__global__ __launch_bounds__(256) void agg_kernel(
    const __half* __restrict__ s, const float* __restrict__ dinv,
    const int* __restrict__ offs, const int* __restrict__ counts,
    const int* __restrict__ rows_sorted, const float* __restrict__ bias,
    __half* __restrict__ outp, int N, int do_relu){
  int slice = blockIdx.x & 7;
  int nodeg = blockIdx.x >> 3;
  int wavei = threadIdx.x >> 6;
  int lane  = threadIdx.x & 63;
  int c = nodeg * 4 + wavei;
  if (c >= N) return;
  int g = lane >> 3, h = lane & 7;
  const __half* sb = s + (size_t)slice * N * 16;
  float ax = 0.f, ay = 0.f;
  if (g == 0){
    float2 f = __half22float2(*(const __half2*)(sb + (size_t)c * 16 + 2 * h));
    ax = f.x; ay = f.y;
  }
  int off = offs[c], cnt = counts[c];
  for (int chunk = 0; chunk < cnt; chunk += 64){
    int nn = min(64, cnt - chunk);
    int myidx = (lane < nn) ? rows_sorted[off + chunk + lane] : 0;
    int jmax = (nn + 7) >> 3;
    #pragma unroll 2
    for (int j = 0; j < jmax; j++){
      int e = 8 * j + g;
      int r = __shfl(myidx, e & 63, 64);
      if (e < nn){
        float2 f = __half22float2(*(const __half2*)(sb + (size_t)r * 16 + 2 * h));
        ax += f.x; ay += f.y;
      }
    }
  }
  ax += __shfl_xor(ax, 8, 64);  ay += __shfl_xor(ay, 8, 64);
  ax += __shfl_xor(ax, 16, 64); ay += __shfl_xor(ay, 16, 64);
  ax += __shfl_xor(ax, 32, 64); ay += __shfl_xor(ay, 32, 64);
  if (g == 0){
    float di = dinv[c];
    float2 bv = *(const float2*)(bias + slice * 16 + 2 * h);
    float ox = di * ax + bv.x;
    float oy = di * ay + bv.y;
    if (do_relu){ ox = fmaxf(ox, 0.f); oy = fmaxf(oy, 0.f); }
    *(__half2*)(outp + ((size_t)slice * N + c) * 16 + 2 * h) = __floats2half2_rn(ox, oy);
  }
}

// ---------------- pair partial: per-slice 16-ch partial dot; slice = blockIdx%8 ----------------
// lane = 4 pairs x 16: sub<8 -> A half2 sub, sub>=8 -> B half2 (sub-8).
__global__ __launch_bounds__(256) void pairp_kernel(
    const __half* __restrict__ A, const __half* __restrict__ B,
    const int* __restrict__ src, const int* __restrict__ dst,
    const float* __restrict__ bm1, const float* __restrict__ Wm2,
    float* __restrict__ partials, int P, int N){
  int slice = blockIdx.x & 7;
  int bgrp  = blockIdx.x >> 3;
  int nbg   = gridDim.x >> 3;
  int wavei = threadIdx.x >> 6;
  int lane  = threadIdx.x & 63;
  int pr = lane >> 4, sub = lane & 15;
  int isB = sub >> 3, hh = sub & 7;
  int ch = slice * 16 + 2 * hh;
  float2 bb = make_float2(bm1[ch], bm1[ch + 1]);
  float2 ww = make_float2(Wm2[ch], Wm2[ch + 1]);
  const __half* basep = isB ? (B + (size_t)slice * N * 16) : (A + (size_t)slice * N * 16);
  float* pout = partials + (size_t)slice * P;
  for (int p0 = (bgrp * 4 + wavei) * 4; p0 < P; p0 += nbg * 16){
    int pi = p0 + pr;
    int piX = (pi < P) ? pi : P - 1;
    int node = isB ? dst[piX] : src[piX];
    float2 f = __half22float2(*(const __half2*)(basep + (size_t)node * 16 + 2 * hh));
    float ox = __shfl_xor(f.x, 8, 64);   // A lanes receive B value (and vice versa)
    float oy = __shfl_xor(f.y, 8, 64);
    float z0 = fmaxf(f.x + ox + bb.x, 0.f);
    float z1 = fmaxf(f.y + oy + bb.y, 0.f);
    float partial = z0 * ww.x + z1 * ww.y;
    partial += __shfl_xor(partial, 1, 64);
    partial += __shfl_xor(partial, 2, 64);
    partial += __shfl_xor(partial, 4, 64);
    if (sub == 0 && pi < P) pout[pi] = partial;
  }
}

__global__ void pairr_kernel(const float* __restrict__ partials,
                             const float* __restrict__ bm2,
                             float* __restrict__ outp, int P){
  int p = blockIdx.x * blockDim.x + threadIdx.x;
  if (p < P){
    float v = bm2[0];
    #pragma unroll
    for (int s = 0; s < NSL; s++) v += partials[(size_t)s * P + p];
    outp[p] = v;
  }
}

// ---------------- launch ----------------

extern "C" void kernel_launch(void* const* d_in, const int* in_sizes, int n_in,
                              void* d_out, int out_size, void* d_ws, size_t ws_size,
                              hipStream_t stream){
  const float* x   = (const float*)d_in[0];
  const int*   ei  = (const int*)  d_in[1];
  const int*   ep  = (const int*)  d_in[2];
  const float* W1  = (const float*)d_in[3];
  const float* b1  = (const float*)d_in[4];
  const float* W2  = (const float*)d_in[5];
  const float* b2  = (const float*)d_in[6];
  const float* Wm1 = (const float*)d_in[7];
  const float* bm1 = (const float*)d_in[8];
  const float* Wm2 = (const float*)d_in[9];
  const float* bm2 = (const float*)d_in[10];
  float* outp = (float*)d_out;

  const int N = in_sizes[0] / NCH;
  const int E = in_sizes[1] / 2;
  const int P = in_sizes[2] / 2;
  const int NB = (N + G_NODES - 1) / G_NODES;

  char* base = (char*)d_ws;
  size_t off = 0;
  int*      counts      = (int*)     (base + off); off = align256(off + (size_t)N * 4);
  int*      offs        = (int*)     (base + off); off = align256(off + (size_t)N * 4);
  float*    dinv        = (float*)   (base + off); off = align256(off + (size_t)N * 4);
  int*      gcur        = (int*)     (base + off); off = align256(off + (size_t)NB * 4);
  int*      bbase       = (int*)     (base + off); off = align256(off + (size_t)NB * 4);
  unsigned* bucketed    = (unsigned*)(base + off); off = align256(off + (size_t)NB * RCAP * 4);
  int*      rows_sorted = (int*)     (base + off); off = align256(off + (size_t)E * 4);
  short*    planes      = (short*)   (base + off); off = align256(off + (size_t)8 * 16384 * 2);
  __half*   sbuf        = (__half*)  (base + off); off = align256(off + (size_t)N * NCH * 2);
  __half*   hbuf        = (__half*)  (base + off); off = align256(off + (size_t)N * NCH * 2);
  __half*   sA          = (__half*)  (base + off); off = align256(off + (size_t)N * NCH * 2);
  __half*   sB          = (__half*)  (base + off); off = align256(off + (size_t)N * NCH * 2);
  float*    partials    = (float*)   (base + off); off = align256(off + (size_t)NSL * P * 4);
  (void)ws_size; (void)n_in; (void)out_size;

  short* W1hi = planes + 0 * 16384;
  short* W1lo = planes + 1 * 16384;
  short* W2hi = planes + 2 * 16384;
  short* W2lo = planes + 3 * 16384;
  short* Wahi = planes + 4 * 16384;
  short* Walo = planes + 5 * 16384;
  short* Wbhi = planes + 6 * 16384;
  short* Wblo = planes + 7 * 16384;

  const int* row = ei;       // edge_index[0] = source
  const int* col = ei + E;   // edge_index[1] = target
  const int* psrc = ep;
  const int* pdst = ep + P;

  hipMemsetAsync(gcur, 0, (size_t)NB * 4, stream);

  binA_kernel <<<(E + EPB - 1) / EPB, 256, 0, stream>>>(row, col, gcur, bucketed, E, NB);
  bscan_kernel<<<1, 256, 0, stream>>>(gcur, bbase, NB);
  binB_kernel <<<NB, 256, 0, stream>>>(bucketed, gcur, bbase, rows_sorted, offs, counts, dinv, N);
  wprep_kernel<<<256, 256, 0, stream>>>(W1, W2, Wm1, planes);

  int gemm_grid = (N + 127) / 128;
  int agg_grid  = 8 * ((N + 3) / 4);

  // conv1: s1 = fp16(dinv*(x@W1)) sliced; h1 = fp16(relu(dinv*(s1[c]+sum s1[r]) + b1)) sliced
  gemm_f32<<<gemm_grid, 512, 0, stream>>>(x, W1hi, W1lo, dinv, sbuf, N, 1);
  agg_kernel<<<agg_grid, 256, 0, stream>>>(sbuf, dinv, offs, counts, rows_sorted, b1, hbuf, N, 1);
  // conv2
  gemm_f16k<8><<<gemm_grid, 512, 0, stream>>>(hbuf, W2hi, W2lo, W2hi, W2lo, dinv, sbuf, sbuf, N, 1);
  agg_kernel<<<agg_grid, 256, 0, stream>>>(sbuf, dinv, offs, counts, rows_sorted, b2, hbuf, N, 0);
  // pair precompute (dual): sA = h2@Wm1a, sB = h2@Wm1b (sliced fp16)
  gemm_f16k<16><<<gemm_grid, 512, 0, stream>>>(hbuf, Wahi, Walo, Wbhi, Wblo, dinv, sA, sB, N, 0);
  // pair head: per-slice partial dots + reduce
  pairp_kernel<<<16384, 256, 0, stream>>>(sA, sB, psrc, pdst, bm1, Wm2, partials, P, N);
  pairr_kernel<<<(P + 255) / 256, 256, 0, stream>>>(partials, bm2, outp, P);
}

// Round 8
// 500.116 us; speedup vs baseline: 1.6583x; 1.6583x over previous
//
#include <hip/hip_runtime.h>
#include <hip/hip_fp16.h>

#define NCH 128
#define G_NODES 256      // nodes per bucket
#define EPB 4096         // edges per block, pass A
#define RCAP 4864        // per-bucket edge capacity
#define MAXNB 512        // max buckets (N <= 128k)
#define KST 40           // W-tile LDS row stride (shorts)
#define XST 136          // fused A-tile LDS row stride (shorts), 272B rows

typedef __attribute__((ext_vector_type(8))) short short8;
typedef _Float16 half8 __attribute__((ext_vector_type(8)));
typedef __attribute__((ext_vector_type(4))) float floatx4;

static inline size_t align256(size_t x){ return (x + 255) & ~(size_t)255; }

// ---------------- Pass A: LDS-binned edge bucketing ----------------
__global__ __launch_bounds__(256) void binA_kernel(
    const int* __restrict__ row, const int* __restrict__ col,
    int* __restrict__ gcur, unsigned* __restrict__ bucketed, int E, int NB){
  __shared__ int cnt[MAXNB];
  __shared__ int lbase[MAXNB];
  __shared__ int gbase[MAXNB];
  __shared__ unsigned sorted[EPB];
  __shared__ unsigned short binOf[EPB];
  __shared__ int sh[256];
  __shared__ int carry;
  int t = threadIdx.x;
  int e0 = blockIdx.x * EPB;
  int ecnt = min(EPB, E - e0);
  for (int i = t; i < NB; i += 256) cnt[i] = 0;
  if (t == 0) carry = 0;
  __syncthreads();
  unsigned rec[16]; int bn[16]; int rk[16];
  #pragma unroll
  for (int i = 0; i < 16; i++){
    int e = e0 + i * 256 + t;
    if (e < E){
      int r = row[e], c = col[e];
      bn[i]  = c >> 8;
      rec[i] = (unsigned)r | ((unsigned)(c & 255) << 17);
      rk[i]  = atomicAdd(&cnt[bn[i]], 1);
    } else bn[i] = -1;
  }
  __syncthreads();
  for (int start = 0; start < NB; start += 256){
    int i = start + t;
    int v = (i < NB) ? cnt[i] : 0;
    sh[t] = v; __syncthreads();
    for (int off = 1; off < 256; off <<= 1){
      int val = (t >= off) ? sh[t - off] : 0;
      __syncthreads(); sh[t] += val; __syncthreads();
    }
    if (i < NB) lbase[i] = sh[t] - v + carry;
    __syncthreads();
    if (t == 255) carry += sh[255];
    __syncthreads();
  }
  for (int i = t; i < NB; i += 256){
    int c = cnt[i];
    gbase[i] = (c > 0) ? atomicAdd(&gcur[i], c) : 0;
  }
  __syncthreads();
  #pragma unroll
  for (int i = 0; i < 16; i++){
    if (bn[i] >= 0){
      int pos = lbase[bn[i]] + rk[i];
      sorted[pos] = rec[i];
      binOf[pos]  = (unsigned short)bn[i];
    }
  }
  __syncthreads();
  for (int idx = t; idx < ecnt; idx += 256){
    int b = binOf[idx];
    int gpos = gbase[b] + (idx - lbase[b]);
    if (gpos < RCAP) bucketed[(size_t)b * RCAP + gpos] = sorted[idx];
  }
}

__global__ void bscan_kernel(const int* __restrict__ gcur, int* __restrict__ bbase, int nb){
  __shared__ int sh[256];
  __shared__ int carry;
  int t = threadIdx.x;
  if (t == 0) carry = 0;
  __syncthreads();
  for (int start = 0; start < nb; start += 256){
    int i = start + t;
    int v = (i < nb) ? min(gcur[i], RCAP) : 0;
    int orig = v;
    sh[t] = v; __syncthreads();
    for (int off = 1; off < 256; off <<= 1){
      int val = (t >= off) ? sh[t - off] : 0;
      __syncthreads(); sh[t] += val; __syncthreads();
    }
    if (i < nb) bbase[i] = sh[t] - orig + carry;
    __syncthreads();
    if (t == 255) carry += sh[255];
    __syncthreads();
  }
}

// ---------------- Pass B: per-bucket LDS counting sort -> final CSR ----------------
__global__ __launch_bounds__(256) void binB_kernel(
    const unsigned* __restrict__ bucketed, const int* __restrict__ gcur,
    const int* __restrict__ bbase, int* __restrict__ rows_sorted,
    int* __restrict__ offs, int* __restrict__ counts, float* __restrict__ dinv, int N){
  __shared__ unsigned ledge[RCAP];
  __shared__ int cnt[G_NODES];
  __shared__ int cnt2[G_NODES];
  __shared__ int lex[G_NODES];
  __shared__ int sh[256];
  int b = blockIdx.x, t = threadIdx.x;
  int size = min(gcur[b], RCAP);
  int base = bbase[b];
  int n0 = b * G_NODES;
  cnt[t] = 0; cnt2[t] = 0;
  __syncthreads();
  for (int i = t; i < size; i += 256){
    unsigned v = bucketed[(size_t)b * RCAP + i];
    ledge[i] = v;
    atomicAdd(&cnt[v >> 17], 1);
  }
  __syncthreads();
  {
    int v = cnt[t];
    sh[t] = v; __syncthreads();
    for (int off = 1; off < 256; off <<= 1){
      int val = (t >= off) ? sh[t - off] : 0;
      __syncthreads(); sh[t] += val; __syncthreads();
    }
    lex[t] = sh[t] - v;
    int n = n0 + t;
    if (n < N){
      counts[n] = v;
      offs[n]   = base + sh[t] - v;
      dinv[n]   = rsqrtf((float)v + 1.0f);
    }
  }
  __syncthreads();
  for (int i = t; i < size; i += 256){
    unsigned v = ledge[i];
    int node = v >> 17;
    int pos = lex[node] + atomicAdd(&cnt2[node], 1);
    rows_sorted[base + pos] = (int)(v & 0x1FFFFu);
  }
}

// ---------------- W prep ----------------
__global__ void wprep_kernel(const float* __restrict__ W1, const float* __restrict__ W2,
                             const float* __restrict__ Wm1, short* __restrict__ planes){
  int mat = blockIdx.x >> 6;
  int idx = ((blockIdx.x & 63) << 8) + threadIdx.x;   // 0..16383
  int k = idx >> 7, n = idx & 127;
  const float* src = (mat == 0) ? W1 : (mat == 1) ? W2 : (mat == 2) ? Wm1 : (Wm1 + 16384);
  float x = src[idx];
  short hs, ls;
  if (mat == 0){
    unsigned u = __float_as_uint(x);
    hs = (short)(u >> 16);
    float hf = __uint_as_float(u & 0xFFFF0000u);
    ls = (short)(__float_as_uint(x - hf) >> 16);
  } else {
    __half h = __float2half(x);
    __half l = __float2half(x - __half2float(h));
    hs = __half_as_short(h); ls = __half_as_short(l);
  }
  planes[(size_t)(2 * mat) * 16384 + n * 128 + k]     = hs;
  planes[(size_t)(2 * mat + 1) * 16384 + n * 128 + k] = ls;
}

// ---------------- GEMM (fp32 input): 3-MFMA bf16 split, row-major fp16 out ----------------
__global__ __launch_bounds__(512, 4) void gemm_f32(
    const float* __restrict__ X, const short* __restrict__ Whi_,
    const short* __restrict__ Wlo_, const float* __restrict__ scale,
    __half* __restrict__ O, int nrows, int do_scale){
  __shared__ short Xhi[128 * KST];
  __shared__ short Xlo[128 * KST];
  __shared__ short Whi[128 * KST];
  __shared__ short Wlo[128 * KST];
  int t = threadIdx.x;
  int w = t >> 6, lane = t & 63;
  int m = lane & 15, q = lane >> 4;
  int row0 = blockIdx.x * 128;
  floatx4 acc[8];
  #pragma unroll
  for (int ct = 0; ct < 8; ct++) acc[ct] = (floatx4)0.f;

  for (int kc = 0; kc < 4; kc++){
    int k0 = kc * 32;
    __syncthreads();
    #pragma unroll
    for (int qq = 0; qq < 2; qq++){
      int f = t + 512 * qq;
      int r = f >> 3, kq = f & 7;
      int gr = row0 + r;
      int grc = (gr < nrows) ? gr : 0;
      float4 v = *(const float4*)(X + (size_t)grc * NCH + k0 + kq * 4);
      short h[4], l[4];
      float vv[4] = {v.x, v.y, v.z, v.w};
      #pragma unroll
      for (int j = 0; j < 4; j++){
        unsigned u = __float_as_uint(vv[j]);
        h[j] = (short)(u >> 16);
        float hf = __uint_as_float(u & 0xFFFF0000u);
        l[j] = (short)(__float_as_uint(vv[j] - hf) >> 16);
      }
      *(uint2*)(Xhi + r * KST + kq * 4) = *(uint2*)h;
      *(uint2*)(Xlo + r * KST + kq * 4) = *(uint2*)l;
    }
    {
      int n = t >> 2, kq = t & 3;
      *(uint4*)(Whi + n * KST + kq * 8) = *(const uint4*)(Whi_ + n * NCH + k0 + kq * 8);
      *(uint4*)(Wlo + n * KST + kq * 8) = *(const uint4*)(Wlo_ + n * NCH + k0 + kq * 8);
    }
    __syncthreads();
    short8 a_hi = *(const short8*)(Xhi + (w * 16 + m) * KST + q * 8);
    short8 a_lo = *(const short8*)(Xlo + (w * 16 + m) * KST + q * 8);
    #pragma unroll
    for (int ct = 0; ct < 8; ct++){
      short8 b_hi = *(const short8*)(Whi + (ct * 16 + m) * KST + q * 8);
      short8 b_lo = *(const short8*)(Wlo + (ct * 16 + m) * KST + q * 8);
      acc[ct] = __builtin_amdgcn_mfma_f32_16x16x32_bf16(a_hi, b_hi, acc[ct], 0, 0, 0);
      acc[ct] = __builtin_amdgcn_mfma_f32_16x16x32_bf16(a_lo, b_hi, acc[ct], 0, 0, 0);
      acc[ct] = __builtin_amdgcn_mfma_f32_16x16x32_bf16(a_hi, b_lo, acc[ct], 0, 0, 0);
    }
  }
  #pragma unroll
  for (int r = 0; r < 4; r++){
    int grow = row0 + w * 16 + q * 4 + r;
    if (grow < nrows){
      float sc = do_scale ? scale[grow] : 1.0f;
      #pragma unroll
      for (int ct = 0; ct < 8; ct++)
        O[(size_t)grow * NCH + ct * 16 + m] = __float2half(acc[ct][r] * sc);
    }
  }
}

// ---------------- Fused agg + GEMM ----------------
// Phase 1: block aggregates 128 nodes (wave per node, 16 nodes/wave) from gather
// table s into LDS as fp16 h-rows (bias + optional relu applied).
// Phase 2: h-tile @ W (2-MFMA f16 split) -> O0[, O1], optional dinv scale.
template<int NCT>
__global__ __launch_bounds__(512, 2) void agg_gemm(
    const __half* __restrict__ s, const float* __restrict__ dinv,
    const int* __restrict__ offs, const int* __restrict__ counts,
    const int* __restrict__ rows_sorted, const float* __restrict__ bias,
    int do_relu,
    const short* __restrict__ Whi0, const short* __restrict__ Wlo0,
    const short* __restrict__ Whi1, const short* __restrict__ Wlo1,
    const float* __restrict__ scale, int do_scale,
    __half* __restrict__ O0, __half* __restrict__ O1, int nrows){
  __shared__ short Xs[128 * XST];          // h tile, fp16
  __shared__ short Whs[NCT * 16 * KST];
  __shared__ short Wls[NCT * 16 * KST];
  int t = threadIdx.x;
  int w = t >> 6, lane = t & 63;
  int row0 = blockIdx.x * 128;

  // ---- phase 1: aggregate ----
  {
    int g = lane >> 4, h = lane & 15;
    for (int i = 0; i < 16; i++){
      int local = w * 16 + i;
      int c = row0 + local;
      float acc[8] = {0.f,0.f,0.f,0.f,0.f,0.f,0.f,0.f};
      if (c < nrows){
        if (g == 0){
          uint4 v = *(const uint4*)(s + (size_t)c * NCH + h * 8);
          const __half2* hp = (const __half2*)&v;
          #pragma unroll
          for (int k = 0; k < 4; k++){
            float2 f = __half22float2(hp[k]);
            acc[2*k] += f.x; acc[2*k+1] += f.y;
          }
        }
        int off = offs[c], cnt = counts[c];
        for (int chunk = 0; chunk < cnt; chunk += 64){
          int nn = min(64, cnt - chunk);
          int myidx = (lane < nn) ? rows_sorted[off + chunk + lane] : 0;
          int jmax = (nn + 3) >> 2;
          #pragma unroll 4
          for (int j = 0; j < jmax; j++){
            int e = 4 * j + g;
            int r = __shfl(myidx, e & 63, 64);
            if (e < nn){
              uint4 v = *(const uint4*)(s + (size_t)r * NCH + h * 8);
              const __half2* hp = (const __half2*)&v;
              #pragma unroll
              for (int k = 0; k < 4; k++){
                float2 f = __half22float2(hp[k]);
                acc[2*k] += f.x; acc[2*k+1] += f.y;
              }
            }
          }
        }
      }
      #pragma unroll
      for (int k = 0; k < 8; k++){
        acc[k] += __shfl_xor(acc[k], 16, 64);
        acc[k] += __shfl_xor(acc[k], 32, 64);
      }
      if (g == 0){
        __half2 packed[4];
        if (c < nrows){
          float di = dinv[c];
          float4 b0 = *(const float4*)(bias + h * 8);
          float4 b1 = *(const float4*)(bias + h * 8 + 4);
          float o[8];
          o[0]=di*acc[0]+b0.x; o[1]=di*acc[1]+b0.y; o[2]=di*acc[2]+b0.z; o[3]=di*acc[3]+b0.w;
          o[4]=di*acc[4]+b1.x; o[5]=di*acc[5]+b1.y; o[6]=di*acc[6]+b1.z; o[7]=di*acc[7]+b1.w;
          if (do_relu){
            #pragma unroll
            for (int k = 0; k < 8; k++) o[k] = fmaxf(o[k], 0.f);
          }
          #pragma unroll
          for (int k = 0; k < 4; k++) packed[k] = __floats2half2_rn(o[2*k], o[2*k+1]);
        } else {
          #pragma unroll
          for (int k = 0; k < 4; k++) packed[k] = __floats2half2_rn(0.f, 0.f);
        }
        *(uint4*)(Xs + local * XST + h * 8) = *(uint4*)packed;
      }
    }
  }

  // ---- phase 2: GEMM from LDS h-tile ----
  int m = lane & 15, q = lane >> 4;
  floatx4 acc2[NCT];
  #pragma unroll
  for (int ct = 0; ct < NCT; ct++) acc2[ct] = (floatx4)0.f;

  for (int kc = 0; kc < 4; kc++){
    int k0 = kc * 32;
    __syncthreads();       // first iter: Xs complete; later: previous W reads done
    #pragma unroll
    for (int i = t; i < NCT * 16 * 4; i += 512){
      int n = i >> 2, kq = i & 3;
      const short* sh = (n < 128) ? (Whi0 + n * NCH) : (Whi1 + (n - 128) * NCH);
      const short* sl = (n < 128) ? (Wlo0 + n * NCH) : (Wlo1 + (n - 128) * NCH);
      *(uint4*)(Whs + n * KST + kq * 8) = *(const uint4*)(sh + k0 + kq * 8);
      *(uint4*)(Wls + n * KST + kq * 8) = *(const uint4*)(sl + k0 + kq * 8);
    }
    __syncthreads();
    half8 a = *(const half8*)(Xs + (w * 16 + m) * XST + k0 + q * 8);
    #pragma unroll
    for (int ct = 0; ct < NCT; ct++){
      half8 bh = *(const half8*)(Whs + (ct * 16 + m) * KST + q * 8);
      half8 bl = *(const half8*)(Wls + (ct * 16 + m) * KST + q * 8);
      acc2[ct] = __builtin_amdgcn_mfma_f32_16x16x32_f16(a, bh, acc2[ct], 0, 0, 0);
      acc2[ct] = __builtin_amdgcn_mfma_f32_16x16x32_f16(a, bl, acc2[ct], 0, 0, 0);
    }
  }
  #pragma unroll
  for (int r = 0; r < 4; r++){
    int grow = row0 + w * 16 + q * 4 + r;
    if (grow < nrows){
      float sc = do_scale ? scale[grow] : 1.0f;
      #pragma unroll
      for (int ct = 0; ct < NCT; ct++){
        __half val = __float2half(acc2[ct][r] * sc);
        if (ct < 8) O0[(size_t)grow * NCH + ct * 16 + m] = val;
        else        O1[(size_t)grow * NCH + (ct - 8) * 16 + m] = val;
      }
    }
  }
}

// ---------------- Pair head: wave per 2 pairs, 16B/lane ----------------
__global__ __launch_bounds__(256) void pair_kernel(
    const __half* __restrict__ A, const __half* __restrict__ B,
    const int* __restrict__ src, const int* __restrict__ dst,
    const float* __restrict__ bm1, const float* __restrict__ Wm2,
    const float* __restrict__ bm2, float* __restrict__ outp, int P){
  int gwave = (int)((blockIdx.x * blockDim.x + threadIdx.x) >> 6);
  int lane  = threadIdx.x & 63;
  int nw    = (int)((gridDim.x * blockDim.x) >> 6);
  int g = lane >> 4, h = lane & 15;
  float bb[8], ww[8];
  {
    float4 t0 = *(const float4*)(bm1 + h * 8);
    float4 t1 = *(const float4*)(bm1 + h * 8 + 4);
    bb[0]=t0.x; bb[1]=t0.y; bb[2]=t0.z; bb[3]=t0.w;
    bb[4]=t1.x; bb[5]=t1.y; bb[6]=t1.z; bb[7]=t1.w;
    float4 w0 = *(const float4*)(Wm2 + h * 8);
    float4 w1 = *(const float4*)(Wm2 + h * 8 + 4);
    ww[0]=w0.x; ww[1]=w0.y; ww[2]=w0.z; ww[3]=w0.w;
    ww[4]=w1.x; ww[5]=w1.y; ww[6]=w1.z; ww[7]=w1.w;
  }
  float bsc = bm2[0];
  const __half* basep = (g & 1) ? B : A;
  for (int p0 = gwave * 2; p0 < P; p0 += nw * 2){
    int pi = p0 + (g >> 1);
    int piX = (pi < P) ? pi : p0;
    int node = (g & 1) ? dst[piX] : src[piX];
    uint4 v = *(const uint4*)(basep + (size_t)node * NCH + h * 8);
    const __half2* hp = (const __half2*)&v;
    float f[8];
    #pragma unroll
    for (int i = 0; i < 4; i++){
      float2 t2 = __half22float2(hp[i]);
      f[2*i] = t2.x; f[2*i+1] = t2.y;
    }
    float partial = 0.f;
    #pragma unroll
    for (int i = 0; i < 8; i++){
      float other = __shfl_xor(f[i], 16, 64);
      float zi = fmaxf(f[i] + other + bb[i], 0.f);
      partial += zi * ww[i];
    }
    partial += __shfl_xor(partial, 1, 64);
    partial += __shfl_xor(partial, 2, 64);
    partial += __shfl_xor(partial, 4, 64);
    partial += __shfl_xor(partial, 8, 64);
    if ((lane & 31) == 0 && pi < P) outp[pi] = partial + bsc;
  }
}

// ---------------- launch ----------------

extern "C" void kernel_launch(void* const* d_in, const int* in_sizes, int n_in,
                              void* d_out, int out_size, void* d_ws, size_t ws_size,
                              hipStream_t stream){
  const float* x   = (const float*)d_in[0];
  const int*   ei  = (const int*)  d_in[1];
  const int*   ep  = (const int*)  d_in[2];
  const float* W1  = (const float*)d_in[3];
  const float* b1  = (const float*)d_in[4];
  const float* W2  = (const float*)d_in[5];
  const float* b2  = (const float*)d_in[6];
  const float* Wm1 = (const float*)d_in[7];
  const float* bm1 = (const float*)d_in[8];
  const float* Wm2 = (const float*)d_in[9];
  const float* bm2 = (const float*)d_in[10];
  float* outp = (float*)d_out;

  const int N = in_sizes[0] / NCH;
  const int E = in_sizes[1] / 2;
  const int P = in_sizes[2] / 2;
  const int NB = (N + G_NODES - 1) / G_NODES;

  char* base = (char*)d_ws;
  size_t off = 0;
  int*      counts      = (int*)     (base + off); off = align256(off + (size_t)N * 4);
  int*      offs        = (int*)     (base + off); off = align256(off + (size_t)N * 4);
  float*    dinv        = (float*)   (base + off); off = align256(off + (size_t)N * 4);
  int*      gcur        = (int*)     (base + off); off = align256(off + (size_t)NB * 4);
  int*      bbase       = (int*)     (base + off); off = align256(off + (size_t)NB * 4);
  unsigned* bucketed    = (unsigned*)(base + off); off = align256(off + (size_t)NB * RCAP * 4);
  int*      rows_sorted = (int*)     (base + off); off = align256(off + (size_t)E * 4);
  short*    planes      = (short*)   (base + off); off = align256(off + (size_t)8 * 16384 * 2);
  __half*   s1buf       = (__half*)  (base + off); off = align256(off + (size_t)N * NCH * 2);
  __half*   s2buf       = (__half*)  (base + off); off = align256(off + (size_t)N * NCH * 2);
  __half*   sA          = (__half*)  (base + off); off = align256(off + (size_t)N * NCH * 2);
  __half*   sB          = (__half*)  (base + off); off = align256(off + (size_t)N * NCH * 2);
  (void)ws_size; (void)n_in; (void)out_size;

  short* W1hi = planes + 0 * 16384;
  short* W1lo = planes + 1 * 16384;
  short* W2hi = planes + 2 * 16384;
  short* W2lo = planes + 3 * 16384;
  short* Wahi = planes + 4 * 16384;
  short* Walo = planes + 5 * 16384;
  short* Wbhi = planes + 6 * 16384;
  short* Wblo = planes + 7 * 16384;

  const int* row = ei;       // edge_index[0] = source
  const int* col = ei + E;   // edge_index[1] = target
  const int* psrc = ep;
  const int* pdst = ep + P;

  hipMemsetAsync(gcur, 0, (size_t)NB * 4, stream);

  binA_kernel <<<(E + EPB - 1) / EPB, 256, 0, stream>>>(row, col, gcur, bucketed, E, NB);
  bscan_kernel<<<1, 256, 0, stream>>>(gcur, bbase, NB);
  binB_kernel <<<NB, 256, 0, stream>>>(bucketed, gcur, bbase, rows_sorted, offs, counts, dinv, N);
  wprep_kernel<<<256, 256, 0, stream>>>(W1, W2, Wm1, planes);

  int gemm_grid = (N + 127) / 128;

  // conv1 transform: s1 = fp16(dinv*(x@W1))
  gemm_f32<<<gemm_grid, 512, 0, stream>>>(x, W1hi, W1lo, dinv, s1buf, N, 1);
  // fused conv1-agg + conv2 transform: h1 = relu(dinv*(s1[c]+sum)+b1) in LDS; s2 = fp16(dinv*(h1@W2))
  agg_gemm<8><<<gemm_grid, 512, 0, stream>>>(s1buf, dinv, offs, counts, rows_sorted, b1, 1,
                                             W2hi, W2lo, W2hi, W2lo, dinv, 1, s2buf, s2buf, N);
  // fused conv2-agg + pair transform: h2 = dinv*(s2[c]+sum)+b2 in LDS; sA = h2@Wm1a, sB = h2@Wm1b
  agg_gemm<16><<<gemm_grid, 512, 0, stream>>>(s2buf, dinv, offs, counts, rows_sorted, b2, 0,
                                              Wahi, Walo, Wbhi, Wblo, dinv, 0, sA, sB, N);
  // out[p] = relu(A[src]+B[dst]+bm1)@Wm2 + bm2
  pair_kernel<<<8192, 256, 0, stream>>>(sA, sB, psrc, pdst, bm1, Wm2, bm2, outp, P);
}

// Round 10
// 395.319 us; speedup vs baseline: 2.0980x; 1.2651x over previous
//
#include <hip/hip_runtime.h>
#include <hip/hip_fp16.h>

#define NCH 128
#define G_NODES 256      // nodes per bucket
#define EPB 4096         // edges per block, pass A
#define RCAP 4864        // per-bucket edge capacity (fixed slab stride)
#define MAXNB 512        // max buckets (N <= 128k)
#define KST 40           // LDS row stride in shorts (80B -> 2-way conflict = free)

typedef __attribute__((ext_vector_type(8))) short short8;
typedef _Float16 half8 __attribute__((ext_vector_type(8)));
typedef __attribute__((ext_vector_type(4))) float floatx4;

static inline size_t align256(size_t x){ return (x + 255) & ~(size_t)255; }

// ---------------- Pass A: LDS-binned edge bucketing ----------------
__global__ __launch_bounds__(256) void binA_kernel(
    const int* __restrict__ row, const int* __restrict__ col,
    int* __restrict__ gcur, unsigned* __restrict__ bucketed, int E, int NB){
  __shared__ int cnt[MAXNB];
  __shared__ int lbase[MAXNB];
  __shared__ int gbase[MAXNB];
  __shared__ unsigned sorted[EPB];
  __shared__ unsigned short binOf[EPB];
  __shared__ int sh[256];
  __shared__ int carry;
  int t = threadIdx.x;
  int e0 = blockIdx.x * EPB;
  int ecnt = min(EPB, E - e0);
  for (int i = t; i < NB; i += 256) cnt[i] = 0;
  if (t == 0) carry = 0;
  __syncthreads();
  unsigned rec[16]; int bn[16]; int rk[16];
  #pragma unroll
  for (int i = 0; i < 16; i++){
    int e = e0 + i * 256 + t;
    if (e < E){
      int r = row[e], c = col[e];
      bn[i]  = c >> 8;
      rec[i] = (unsigned)r | ((unsigned)(c & 255) << 17);
      rk[i]  = atomicAdd(&cnt[bn[i]], 1);
    } else bn[i] = -1;
  }
  __syncthreads();
  for (int start = 0; start < NB; start += 256){
    int i = start + t;
    int v = (i < NB) ? cnt[i] : 0;
    sh[t] = v; __syncthreads();
    for (int off = 1; off < 256; off <<= 1){
      int val = (t >= off) ? sh[t - off] : 0;
      __syncthreads(); sh[t] += val; __syncthreads();
    }
    if (i < NB) lbase[i] = sh[t] - v + carry;
    __syncthreads();
    if (t == 255) carry += sh[255];
    __syncthreads();
  }
  for (int i = t; i < NB; i += 256){
    int c = cnt[i];
    gbase[i] = (c > 0) ? atomicAdd(&gcur[i], c) : 0;
  }
  __syncthreads();
  #pragma unroll
  for (int i = 0; i < 16; i++){
    if (bn[i] >= 0){
      int pos = lbase[bn[i]] + rk[i];
      sorted[pos] = rec[i];
      binOf[pos]  = (unsigned short)bn[i];
    }
  }
  __syncthreads();
  for (int idx = t; idx < ecnt; idx += 256){
    int b = binOf[idx];
    int gpos = gbase[b] + (idx - lbase[b]);
    if (gpos < RCAP) bucketed[(size_t)b * RCAP + gpos] = sorted[idx];
  }
}

// ---------------- W prep (+ gcur zeroing) ----------------
__global__ void wprep_kernel(const float* __restrict__ W1, const float* __restrict__ W2,
                             const float* __restrict__ Wm1, short* __restrict__ planes,
                             int* __restrict__ gcur, int NB){
  if (blockIdx.x < 2){
    int i = blockIdx.x * 256 + threadIdx.x;
    if (i < NB) gcur[i] = 0;
  }
  int mat = blockIdx.x >> 6;
  int idx = ((blockIdx.x & 63) << 8) + threadIdx.x;   // 0..16383
  int k = idx >> 7, n = idx & 127;
  const float* src = (mat == 0) ? W1 : (mat == 1) ? W2 : (mat == 2) ? Wm1 : (Wm1 + 16384);
  float x = src[idx];
  short hs, ls;
  if (mat == 0){
    unsigned u = __float_as_uint(x);
    hs = (short)(u >> 16);
    float hf = __uint_as_float(u & 0xFFFF0000u);
    ls = (short)(__float_as_uint(x - hf) >> 16);
  } else {
    __half h = __float2half(x);
    __half l = __float2half(x - __half2float(h));
    hs = __half_as_short(h); ls = __half_as_short(l);
  }
  planes[(size_t)(2 * mat) * 16384 + n * 128 + k]     = hs;
  planes[(size_t)(2 * mat + 1) * 16384 + n * 128 + k] = ls;
}

// ---------------- Fused launch: gemm_f32 (blocks < gemmBlocks) || binB (rest) ----------------
// NOTE: the gemm side writes UNscaled t1 = x@W1 (no dinv read) — dinv is produced
// by the binB side of this same dispatch; scaling is applied downstream in agg.
__global__ __launch_bounds__(512, 3) void fused_gemm_binB(
    const float* __restrict__ X, const short* __restrict__ Whi_,
    const short* __restrict__ Wlo_, __half* __restrict__ O, int nrows, int gemmBlocks,
    const unsigned* __restrict__ bucketed, const int* __restrict__ gcur,
    int* __restrict__ rows_sorted, int* __restrict__ offs,
    int* __restrict__ counts, float* __restrict__ dinv, int N){
  __shared__ __align__(16) char smem[40960];
  int t = threadIdx.x;
  if (blockIdx.x < gemmBlocks){
    short* Xhi = (short*)smem;
    short* Xlo = Xhi + 128 * KST;
    short* Whi = Xlo + 128 * KST;
    short* Wlo = Whi + 128 * KST;
    int w = t >> 6, lane = t & 63;
    int m = lane & 15, q = lane >> 4;
    int row0 = blockIdx.x * 128;
    floatx4 acc[8];
    #pragma unroll
    for (int ct = 0; ct < 8; ct++) acc[ct] = (floatx4)0.f;
    for (int kc = 0; kc < 4; kc++){
      int k0 = kc * 32;
      __syncthreads();
      #pragma unroll
      for (int qq = 0; qq < 2; qq++){
        int f = t + 512 * qq;
        int r = f >> 3, kq = f & 7;
        int gr = row0 + r;
        int grc = (gr < nrows) ? gr : 0;
        float4 v = *(const float4*)(X + (size_t)grc * NCH + k0 + kq * 4);
        short h[4], l[4];
        float vv[4] = {v.x, v.y, v.z, v.w};
        #pragma unroll
        for (int j = 0; j < 4; j++){
          unsigned u = __float_as_uint(vv[j]);
          h[j] = (short)(u >> 16);
          float hf = __uint_as_float(u & 0xFFFF0000u);
          l[j] = (short)(__float_as_uint(vv[j] - hf) >> 16);
        }
        *(uint2*)(Xhi + r * KST + kq * 4) = *(uint2*)h;
        *(uint2*)(Xlo + r * KST + kq * 4) = *(uint2*)l;
      }
      {
        int n = t >> 2, kq = t & 3;
        *(uint4*)(Whi + n * KST + kq * 8) = *(const uint4*)(Whi_ + n * NCH + k0 + kq * 8);
        *(uint4*)(Wlo + n * KST + kq * 8) = *(const uint4*)(Wlo_ + n * NCH + k0 + kq * 8);
      }
      __syncthreads();
      short8 a_hi = *(const short8*)(Xhi + (w * 16 + m) * KST + q * 8);
      short8 a_lo = *(const short8*)(Xlo + (w * 16 + m) * KST + q * 8);
      #pragma unroll
      for (int ct = 0; ct < 8; ct++){
        short8 b_hi = *(const short8*)(Whi + (ct * 16 + m) * KST + q * 8);
        short8 b_lo = *(const short8*)(Wlo + (ct * 16 + m) * KST + q * 8);
        acc[ct] = __builtin_amdgcn_mfma_f32_16x16x32_bf16(a_hi, b_hi, acc[ct], 0, 0, 0);
        acc[ct] = __builtin_amdgcn_mfma_f32_16x16x32_bf16(a_lo, b_hi, acc[ct], 0, 0, 0);
        acc[ct] = __builtin_amdgcn_mfma_f32_16x16x32_bf16(a_hi, b_lo, acc[ct], 0, 0, 0);
      }
    }
    #pragma unroll
    for (int r = 0; r < 4; r++){
      int grow = row0 + w * 16 + q * 4 + r;
      if (grow < nrows){
        #pragma unroll
        for (int ct = 0; ct < 8; ct++)
          O[(size_t)grow * NCH + ct * 16 + m] = __float2half(acc[ct][r]);
      }
    }
  } else {
    // ---- binB: per-bucket LDS counting sort -> CSR (fixed slabs) ----
    int b = blockIdx.x - gemmBlocks;
    unsigned* ledge = (unsigned*)smem;              // RCAP
    int* cnt  = (int*)(smem + RCAP * 4);            // 256
    int* cnt2 = cnt + 256;
    int* lex  = cnt2 + 256;
    int* sh   = lex + 256;
    int size = min(gcur[b], RCAP);
    int n0 = b * G_NODES;
    if (t < 256){ cnt[t] = 0; cnt2[t] = 0; }
    __syncthreads();
    for (int i = t; i < size; i += 512){
      unsigned v = bucketed[(size_t)b * RCAP + i];
      ledge[i] = v;
      atomicAdd(&cnt[v >> 17], 1);
    }
    __syncthreads();
    {
      int v = (t < 256) ? cnt[t] : 0;
      if (t < 256) sh[t] = v;
      __syncthreads();
      for (int off = 1; off < 256; off <<= 1){
        int val = (t >= off && t < 256) ? sh[t - off] : 0;
        __syncthreads();
        if (t < 256) sh[t] += val;
        __syncthreads();
      }
      if (t < 256){
        lex[t] = sh[t] - v;
        int n = n0 + t;
        if (n < N){
          counts[n] = v;
          offs[n]   = b * RCAP + sh[t] - v;
          dinv[n]   = rsqrtf((float)v + 1.0f);
        }
      }
    }
    __syncthreads();
    for (int i = t; i < size; i += 512){
      unsigned v = ledge[i];
      int node = v >> 17;
      int pos = lex[node] + atomicAdd(&cnt2[node], 1);
      rows_sorted[(size_t)b * RCAP + pos] = (int)(v & 0x1FFFFu);
    }
  }
}

// ---------------- GEMM (fp16 input): 2-MFMA f16, NCT col-tiles, unscaled out ----------------
template<int NCT>
__global__ __launch_bounds__(512, 4) void gemm_f16k(
    const __half* __restrict__ X,
    const short* __restrict__ Whi0, const short* __restrict__ Wlo0,
    const short* __restrict__ Whi1, const short* __restrict__ Wlo1,
    __half* __restrict__ O0, __half* __restrict__ O1, int nrows){
  __shared__ short Xs[128 * KST];
  __shared__ short Whs[NCT * 16 * KST];
  __shared__ short Wls[NCT * 16 * KST];
  int t = threadIdx.x;
  int w = t >> 6, lane = t & 63;
  int m = lane & 15, q = lane >> 4;
  int row0 = blockIdx.x * 128;
  floatx4 acc[NCT];
  #pragma unroll
  for (int ct = 0; ct < NCT; ct++) acc[ct] = (floatx4)0.f;

  for (int kc = 0; kc < 4; kc++){
    int k0 = kc * 32;
    __syncthreads();
    {
      int r = t >> 2, kq = t & 3;
      int gr = row0 + r;
      int grc = (gr < nrows) ? gr : 0;
      *(uint4*)(Xs + r * KST + kq * 8) = *(const uint4*)(X + (size_t)grc * NCH + k0 + kq * 8);
    }
    #pragma unroll
    for (int i = t; i < NCT * 16 * 4; i += 512){
      int n = i >> 2, kq = i & 3;
      const short* sh = (n < 128) ? (Whi0 + n * NCH) : (Whi1 + (n - 128) * NCH);
      const short* sl = (n < 128) ? (Wlo0 + n * NCH) : (Wlo1 + (n - 128) * NCH);
      *(uint4*)(Whs + n * KST + kq * 8) = *(const uint4*)(sh + k0 + kq * 8);
      *(uint4*)(Wls + n * KST + kq * 8) = *(const uint4*)(sl + k0 + kq * 8);
    }
    __syncthreads();
    half8 a = *(const half8*)(Xs + (w * 16 + m) * KST + q * 8);
    #pragma unroll
    for (int ct = 0; ct < NCT; ct++){
      half8 bh = *(const half8*)(Whs + (ct * 16 + m) * KST + q * 8);
      half8 bl = *(const half8*)(Wls + (ct * 16 + m) * KST + q * 8);
      acc[ct] = __builtin_amdgcn_mfma_f32_16x16x32_f16(a, bh, acc[ct], 0, 0, 0);
      acc[ct] = __builtin_amdgcn_mfma_f32_16x16x32_f16(a, bl, acc[ct], 0, 0, 0);
    }
  }
  #pragma unroll
  for (int r = 0; r < 4; r++){
    int grow = row0 + w * 16 + q * 4 + r;
    if (grow < nrows){
      #pragma unroll
      for (int ct = 0; ct < NCT; ct++){
        __half val = __float2half(acc[ct][r]);
        if (ct < 8) O0[(size_t)grow * NCH + ct * 16 + m] = val;
        else        O1[(size_t)grow * NCH + (ct - 8) * 16 + m] = val;
      }
    }
  }
}

// ---------------- GCN aggregation: wave per node, 16B/lane gathers ----------------
// t = UNscaled transformed features (fp16). out[c] = maybe_relu(
//   dinv[c] * ( dinv[c]*t[c] + sum_e dinv[r]*t[r] ) + bias ), fp16 out.
// dinv[r] fetched with the coalesced index load (400KB, L2-hot) and shfl-broadcast;
// per-edge scaling rides the existing adds as FMAs (same VALU count).
__global__ __launch_bounds__(256) void agg_kernel(
    const __half* __restrict__ s, const float* __restrict__ dinv,
    const int* __restrict__ offs, const int* __restrict__ counts,
    const int* __restrict__ rows_sorted, const float* __restrict__ bias,
    __half* __restrict__ outp, int N, int do_relu){
  int wave = (int)((blockIdx.x * blockDim.x + threadIdx.x) >> 6);
  int lane = threadIdx.x & 63;
  if (wave >= N) return;
  int c = wave;
  int g = lane >> 4, h = lane & 15;
  float di = dinv[c];
  float acc[8] = {0.f,0.f,0.f,0.f,0.f,0.f,0.f,0.f};
  if (g == 0){
    uint4 v = *(const uint4*)(s + (size_t)c * NCH + h * 8);
    const __half2* hp = (const __half2*)&v;
    #pragma unroll
    for (int i = 0; i < 4; i++){
      float2 f = __half22float2(hp[i]);
      acc[2*i] = fmaf(di, f.x, acc[2*i]); acc[2*i+1] = fmaf(di, f.y, acc[2*i+1]);
    }
  }
  int off = offs[c], cnt = counts[c];
  for (int chunk = 0; chunk < cnt; chunk += 64){
    int nn = min(64, cnt - chunk);
    int myidx = (lane < nn) ? rows_sorted[off + chunk + lane] : 0;
    float mydinv = (lane < nn) ? dinv[myidx] : 0.f;
    int jmax = (nn + 3) >> 2;
    #pragma unroll 4
    for (int j = 0; j < jmax; j++){
      int e = 4 * j + g;
      int r  = __shfl(myidx, e & 63, 64);
      float dr = __shfl(mydinv, e & 63, 64);
      if (e < nn){
        uint4 v = *(const uint4*)(s + (size_t)r * NCH + h * 8);
        const __half2* hp = (const __half2*)&v;
        #pragma unroll
        for (int i = 0; i < 4; i++){
          float2 f = __half22float2(hp[i]);
          acc[2*i] = fmaf(dr, f.x, acc[2*i]); acc[2*i+1] = fmaf(dr, f.y, acc[2*i+1]);
        }
      }
    }
  }
  #pragma unroll
  for (int i = 0; i < 8; i++){
    acc[i] += __shfl_xor(acc[i], 16, 64);
    acc[i] += __shfl_xor(acc[i], 32, 64);
  }
  if (g == 0){
    float4 b0 = *(const float4*)(bias + h * 8);
    float4 b1 = *(const float4*)(bias + h * 8 + 4);
    float o[8];
    o[0] = di*acc[0]+b0.x; o[1] = di*acc[1]+b0.y; o[2] = di*acc[2]+b0.z; o[3] = di*acc[3]+b0.w;
    o[4] = di*acc[4]+b1.x; o[5] = di*acc[5]+b1.y; o[6] = di*acc[6]+b1.z; o[7] = di*acc[7]+b1.w;
    if (do_relu){
      #pragma unroll
      for (int i = 0; i < 8; i++) o[i] = fmaxf(o[i], 0.f);
    }
    __half2 packed[4];
    #pragma unroll
    for (int i = 0; i < 4; i++) packed[i] = __floats2half2_rn(o[2*i], o[2*i+1]);
    *(uint4*)(outp + (size_t)c * NCH + h * 8) = *(uint4*)packed;
  }
}

// ---------------- Pair head: wave per 2 pairs, 16B/lane ----------------
__global__ __launch_bounds__(256) void pair_kernel(
    const __half* __restrict__ A, const __half* __restrict__ B,
    const int* __restrict__ src, const int* __restrict__ dst,
    const float* __restrict__ bm1, const float* __restrict__ Wm2,
    const float* __restrict__ bm2, float* __restrict__ outp, int P){
  int gwave = (int)((blockIdx.x * blockDim.x + threadIdx.x) >> 6);
  int lane  = threadIdx.x & 63;
  int nw    = (int)((gridDim.x * blockDim.x) >> 6);
  int g = lane >> 4, h = lane & 15;
  float bb[8], ww[8];
  {
    float4 t0 = *(const float4*)(bm1 + h * 8);
    float4 t1 = *(const float4*)(bm1 + h * 8 + 4);
    bb[0]=t0.x; bb[1]=t0.y; bb[2]=t0.z; bb[3]=t0.w;
    bb[4]=t1.x; bb[5]=t1.y; bb[6]=t1.z; bb[7]=t1.w;
    float4 w0 = *(const float4*)(Wm2 + h * 8);
    float4 w1 = *(const float4*)(Wm2 + h * 8 + 4);
    ww[0]=w0.x; ww[1]=w0.y; ww[2]=w0.z; ww[3]=w0.w;
    ww[4]=w1.x; ww[5]=w1.y; ww[6]=w1.z; ww[7]=w1.w;
  }
  float bsc = bm2[0];
  const __half* basep = (g & 1) ? B : A;
  for (int p0 = gwave * 2; p0 < P; p0 += nw * 2){
    int pi = p0 + (g >> 1);
    int piX = (pi < P) ? pi : p0;
    int node = (g & 1) ? dst[piX] : src[piX];
    uint4 v = *(const uint4*)(basep + (size_t)node * NCH + h * 8);
    const __half2* hp = (const __half2*)&v;
    float f[8];
    #pragma unroll
    for (int i = 0; i < 4; i++){
      float2 t2 = __half22float2(hp[i]);
      f[2*i] = t2.x; f[2*i+1] = t2.y;
    }
    float partial = 0.f;
    #pragma unroll
    for (int i = 0; i < 8; i++){
      float other = __shfl_xor(f[i], 16, 64);
      float zi = fmaxf(f[i] + other + bb[i], 0.f);
      partial += zi * ww[i];
    }
    partial += __shfl_xor(partial, 1, 64);
    partial += __shfl_xor(partial, 2, 64);
    partial += __shfl_xor(partial, 4, 64);
    partial += __shfl_xor(partial, 8, 64);
    if ((lane & 31) == 0 && pi < P) outp[pi] = partial + bsc;
  }
}

// ---------------- launch ----------------

extern "C" void kernel_launch(void* const* d_in, const int* in_sizes, int n_in,
                              void* d_out, int out_size, void* d_ws, size_t ws_size,
                              hipStream_t stream){
  const float* x   = (const float*)d_in[0];
  const int*   ei  = (const int*)  d_in[1];
  const int*   ep  = (const int*)  d_in[2];
  const float* W1  = (const float*)d_in[3];
  const float* b1  = (const float*)d_in[4];
  const float* W2  = (const float*)d_in[5];
  const float* b2  = (const float*)d_in[6];
  const float* Wm1 = (const float*)d_in[7];
  const float* bm1 = (const float*)d_in[8];
  const float* Wm2 = (const float*)d_in[9];
  const float* bm2 = (const float*)d_in[10];
  float* outp = (float*)d_out;

  const int N = in_sizes[0] / NCH;
  const int E = in_sizes[1] / 2;
  const int P = in_sizes[2] / 2;
  const int NB = (N + G_NODES - 1) / G_NODES;

  char* base = (char*)d_ws;
  size_t off = 0;
  int*      counts      = (int*)     (base + off); off = align256(off + (size_t)N * 4);
  int*      offs        = (int*)     (base + off); off = align256(off + (size_t)N * 4);
  float*    dinv        = (float*)   (base + off); off = align256(off + (size_t)N * 4);
  int*      gcur        = (int*)     (base + off); off = align256(off + (size_t)NB * 4);
  unsigned* bucketed    = (unsigned*)(base + off); off = align256(off + (size_t)NB * RCAP * 4);
  int*      rows_sorted = (int*)     (base + off); off = align256(off + (size_t)NB * RCAP * 4);
  short*    planes      = (short*)   (base + off); off = align256(off + (size_t)8 * 16384 * 2);
  __half*   s1buf       = (__half*)  (base + off); off = align256(off + (size_t)N * NCH * 2);
  __half*   h1buf       = (__half*)  (base + off); off = align256(off + (size_t)N * NCH * 2);
  __half*   s2buf       = (__half*)  (base + off); off = align256(off + (size_t)N * NCH * 2);
  __half*   sA          = (__half*)  (base + off); off = align256(off + (size_t)N * NCH * 2);
  __half*   sB          = (__half*)  (base + off); off = align256(off + (size_t)N * NCH * 2);
  (void)ws_size; (void)n_in; (void)out_size;

  short* W1hi = planes + 0 * 16384;
  short* W1lo = planes + 1 * 16384;
  short* W2hi = planes + 2 * 16384;
  short* W2lo = planes + 3 * 16384;
  short* Wahi = planes + 4 * 16384;
  short* Walo = planes + 5 * 16384;
  short* Wbhi = planes + 6 * 16384;
  short* Wblo = planes + 7 * 16384;

  const int* row = ei;       // edge_index[0] = source
  const int* col = ei + E;   // edge_index[1] = target
  const int* psrc = ep;
  const int* pdst = ep + P;

  int gemm_grid = (N + 127) / 128;
  int agg_grid  = (N + 3) / 4;

  // 1: weight planes + gcur zeroing
  wprep_kernel<<<256, 256, 0, stream>>>(W1, W2, Wm1, planes, gcur, NB);
  // 2: edge bucketing
  binA_kernel<<<(E + EPB - 1) / EPB, 256, 0, stream>>>(row, col, gcur, bucketed, E, NB);
  // 3: fused conv1 GEMM (t1 = x@W1, UNscaled) || CSR finalize (no shared data -> no race)
  fused_gemm_binB<<<gemm_grid + NB, 512, 0, stream>>>(
      x, W1hi, W1lo, s1buf, N, gemm_grid,
      bucketed, gcur, rows_sorted, offs, counts, dinv, N);
  // 4: conv1 agg (applies dinv[r] per edge): h1 = relu(dinv*(dinv*t1[c]+sum dinv[r]t1[r])+b1)
  agg_kernel<<<agg_grid, 256, 0, stream>>>(s1buf, dinv, offs, counts, rows_sorted, b1, h1buf, N, 1);
  // 5: conv2 transform: t2 = h1@W2 (unscaled)
  gemm_f16k<8><<<gemm_grid, 512, 0, stream>>>(h1buf, W2hi, W2lo, W2hi, W2lo, s2buf, s2buf, N);
  // 6: conv2 agg: h2
  agg_kernel<<<agg_grid, 256, 0, stream>>>(s2buf, dinv, offs, counts, rows_sorted, b2, h1buf, N, 0);
  // 7: pair precompute (dual): sA = h2@Wm1a, sB = h2@Wm1b
  gemm_f16k<16><<<gemm_grid, 512, 0, stream>>>(h1buf, Wahi, Walo, Wbhi, Wblo, sA, sB, N);
  // 8: out[p] = relu(A[src]+B[dst]+bm1)@Wm2 + bm2
  pair_kernel<<<8192, 256, 0, stream>>>(sA, sB, psrc, pdst, bm1, Wm2, bm2, outp, P);
}

// Round 11
// 382.801 us; speedup vs baseline: 2.1666x; 1.0327x over previous
//
#include <hip/hip_runtime.h>
#include <hip/hip_fp16.h>

#define NCH 128
#define G_NODES 256      // nodes per bucket
#define EPB 4096         // edges per block, pass A
#define RCAP 4864        // per-bucket edge capacity (fixed slab stride)
#define MAXNB 512        // max buckets (N <= 128k)
#define KST 40           // LDS row stride in shorts (80B -> 2-way conflict = free)

typedef __attribute__((ext_vector_type(8))) short short8;
typedef _Float16 half8 __attribute__((ext_vector_type(8)));
typedef __attribute__((ext_vector_type(4))) float floatx4;

static inline size_t align256(size_t x){ return (x + 255) & ~(size_t)255; }

// ---------------- Pass A: LDS-binned edge bucketing (+ W-prep tail) ----------------
__global__ __launch_bounds__(256) void binA_kernel(
    const int* __restrict__ row, const int* __restrict__ col,
    int* __restrict__ gcur, unsigned* __restrict__ bucketed, int E, int NB,
    const float* __restrict__ W1, const float* __restrict__ W2,
    const float* __restrict__ Wm1, short* __restrict__ planes){
  __shared__ int cnt[MAXNB];
  __shared__ int lbase[MAXNB];
  __shared__ int gbase[MAXNB];
  __shared__ unsigned sorted[EPB];
  __shared__ unsigned short binOf[EPB];
  __shared__ int sh[256];
  __shared__ int carry;
  int t = threadIdx.x;
  int e0 = blockIdx.x * EPB;
  int ecnt = min(EPB, E - e0);
  for (int i = t; i < NB; i += 256) cnt[i] = 0;
  if (t == 0) carry = 0;
  __syncthreads();
  unsigned rec[16]; int bn[16]; int rk[16];
  #pragma unroll
  for (int i = 0; i < 16; i++){
    int e = e0 + i * 256 + t;
    if (e < E){
      int r = row[e], c = col[e];
      bn[i]  = c >> 8;
      rec[i] = (unsigned)r | ((unsigned)(c & 255) << 17);
      rk[i]  = atomicAdd(&cnt[bn[i]], 1);
    } else bn[i] = -1;
  }
  __syncthreads();
  for (int start = 0; start < NB; start += 256){
    int i = start + t;
    int v = (i < NB) ? cnt[i] : 0;
    sh[t] = v; __syncthreads();
    for (int off = 1; off < 256; off <<= 1){
      int val = (t >= off) ? sh[t - off] : 0;
      __syncthreads(); sh[t] += val; __syncthreads();
    }
    if (i < NB) lbase[i] = sh[t] - v + carry;
    __syncthreads();
    if (t == 255) carry += sh[255];
    __syncthreads();
  }
  for (int i = t; i < NB; i += 256){
    int c = cnt[i];
    gbase[i] = (c > 0) ? atomicAdd(&gcur[i], c) : 0;
  }
  __syncthreads();
  #pragma unroll
  for (int i = 0; i < 16; i++){
    if (bn[i] >= 0){
      int pos = lbase[bn[i]] + rk[i];
      sorted[pos] = rec[i];
      binOf[pos]  = (unsigned short)bn[i];
    }
  }
  __syncthreads();
  for (int idx = t; idx < ecnt; idx += 256){
    int b = binOf[idx];
    int gpos = gbase[b] + (idx - lbase[b]);
    if (gpos < RCAP) bucketed[(size_t)b * RCAP + gpos] = sorted[idx];
  }
  // ---- W-prep tail: one element per thread (65536 total over 391*256 threads) ----
  {
    int gid = blockIdx.x * 256 + t;
    if (gid < 4 * 16384){
      int mat = gid >> 14;
      int idx = gid & 16383;
      int k = idx >> 7, n = idx & 127;
      const float* src = (mat == 0) ? W1 : (mat == 1) ? W2 : (mat == 2) ? Wm1 : (Wm1 + 16384);
      float x = src[idx];
      short hs, ls;
      if (mat == 0){
        unsigned u = __float_as_uint(x);
        hs = (short)(u >> 16);
        float hf = __uint_as_float(u & 0xFFFF0000u);
        ls = (short)(__float_as_uint(x - hf) >> 16);
      } else {
        __half h = __float2half(x);
        __half l = __float2half(x - __half2float(h));
        hs = __half_as_short(h); ls = __half_as_short(l);
      }
      planes[(size_t)(2 * mat) * 16384 + n * 128 + k]     = hs;
      planes[(size_t)(2 * mat + 1) * 16384 + n * 128 + k] = ls;
    }
  }
}

// ---------------- Fused launch: gemm_f32 (blocks < gemmBlocks) || binB (rest) ----------------
// gemm side writes UNscaled t1 = x@W1 (dinv produced by binB in same dispatch).
__global__ __launch_bounds__(512, 4) void fused_gemm_binB(
    const float* __restrict__ X, const short* __restrict__ Whi_,
    const short* __restrict__ Wlo_, __half* __restrict__ O, int nrows, int gemmBlocks,
    const unsigned* __restrict__ bucketed, const int* __restrict__ gcur,
    int* __restrict__ rows_sorted, int* __restrict__ offs,
    int* __restrict__ counts, float* __restrict__ dinv, int N){
  __shared__ __align__(16) char smem[40960];
  int t = threadIdx.x;
  if (blockIdx.x < gemmBlocks){
    short* Xhi = (short*)smem;
    short* Xlo = Xhi + 128 * KST;
    short* Whi = Xlo + 128 * KST;
    short* Wlo = Whi + 128 * KST;
    int w = t >> 6, lane = t & 63;
    int m = lane & 15, q = lane >> 4;
    int row0 = blockIdx.x * 128;
    floatx4 acc[8];
    #pragma unroll
    for (int ct = 0; ct < 8; ct++) acc[ct] = (floatx4)0.f;
    for (int kc = 0; kc < 4; kc++){
      int k0 = kc * 32;
      __syncthreads();
      #pragma unroll
      for (int qq = 0; qq < 2; qq++){
        int f = t + 512 * qq;
        int r = f >> 3, kq = f & 7;
        int gr = row0 + r;
        int grc = (gr < nrows) ? gr : 0;
        float4 v = *(const float4*)(X + (size_t)grc * NCH + k0 + kq * 4);
        short h[4], l[4];
        float vv[4] = {v.x, v.y, v.z, v.w};
        #pragma unroll
        for (int j = 0; j < 4; j++){
          unsigned u = __float_as_uint(vv[j]);
          h[j] = (short)(u >> 16);
          float hf = __uint_as_float(u & 0xFFFF0000u);
          l[j] = (short)(__float_as_uint(vv[j] - hf) >> 16);
        }
        *(uint2*)(Xhi + r * KST + kq * 4) = *(uint2*)h;
        *(uint2*)(Xlo + r * KST + kq * 4) = *(uint2*)l;
      }
      {
        int n = t >> 2, kq = t & 3;
        *(uint4*)(Whi + n * KST + kq * 8) = *(const uint4*)(Whi_ + n * NCH + k0 + kq * 8);
        *(uint4*)(Wlo + n * KST + kq * 8) = *(const uint4*)(Wlo_ + n * NCH + k0 + kq * 8);
      }
      __syncthreads();
      short8 a_hi = *(const short8*)(Xhi + (w * 16 + m) * KST + q * 8);
      short8 a_lo = *(const short8*)(Xlo + (w * 16 + m) * KST + q * 8);
      #pragma unroll
      for (int ct = 0; ct < 8; ct++){
        short8 b_hi = *(const short8*)(Whi + (ct * 16 + m) * KST + q * 8);
        short8 b_lo = *(const short8*)(Wlo + (ct * 16 + m) * KST + q * 8);
        acc[ct] = __builtin_amdgcn_mfma_f32_16x16x32_bf16(a_hi, b_hi, acc[ct], 0, 0, 0);
        acc[ct] = __builtin_amdgcn_mfma_f32_16x16x32_bf16(a_lo, b_hi, acc[ct], 0, 0, 0);
        acc[ct] = __builtin_amdgcn_mfma_f32_16x16x32_bf16(a_hi, b_lo, acc[ct], 0, 0, 0);
      }
    }
    #pragma unroll
    for (int r = 0; r < 4; r++){
      int grow = row0 + w * 16 + q * 4 + r;
      if (grow < nrows){
        #pragma unroll
        for (int ct = 0; ct < 8; ct++)
          O[(size_t)grow * NCH + ct * 16 + m] = __float2half(acc[ct][r]);
      }
    }
  } else {
    // ---- binB: per-bucket LDS counting sort -> CSR (fixed slabs) ----
    int b = blockIdx.x - gemmBlocks;
    unsigned* ledge = (unsigned*)smem;              // RCAP
    int* cnt  = (int*)(smem + RCAP * 4);            // 256
    int* cnt2 = cnt + 256;
    int* lex  = cnt2 + 256;
    int* sh   = lex + 256;
    int size = min(gcur[b], RCAP);
    int n0 = b * G_NODES;
    if (t < 256){ cnt[t] = 0; cnt2[t] = 0; }
    __syncthreads();
    for (int i = t; i < size; i += 512){
      unsigned v = bucketed[(size_t)b * RCAP + i];
      ledge[i] = v;
      atomicAdd(&cnt[v >> 17], 1);
    }
    __syncthreads();
    {
      int v = (t < 256) ? cnt[t] : 0;
      if (t < 256) sh[t] = v;
      __syncthreads();
      for (int off = 1; off < 256; off <<= 1){
        int val = (t >= off && t < 256) ? sh[t - off] : 0;
        __syncthreads();
        if (t < 256) sh[t] += val;
        __syncthreads();
      }
      if (t < 256){
        lex[t] = sh[t] - v;
        int n = n0 + t;
        if (n < N){
          counts[n] = v;
          offs[n]   = b * RCAP + sh[t] - v;
          dinv[n]   = rsqrtf((float)v + 1.0f);
        }
      }
    }
    __syncthreads();
    for (int i = t; i < size; i += 512){
      unsigned v = ledge[i];
      int node = v >> 17;
      int pos = lex[node] + atomicAdd(&cnt2[node], 1);
      rows_sorted[(size_t)b * RCAP + pos] = (int)(v & 0x1FFFFu);
    }
  }
}

// ---------------- GEMM (fp16 input): 2-MFMA f16, NCT col-tiles, opt. dinv scale ----------------
template<int NCT>
__global__ __launch_bounds__(512, 4) void gemm_f16k(
    const __half* __restrict__ X,
    const short* __restrict__ Whi0, const short* __restrict__ Wlo0,
    const short* __restrict__ Whi1, const short* __restrict__ Wlo1,
    const float* __restrict__ scale, int do_scale,
    __half* __restrict__ O0, __half* __restrict__ O1, int nrows){
  __shared__ short Xs[128 * KST];
  __shared__ short Whs[NCT * 16 * KST];
  __shared__ short Wls[NCT * 16 * KST];
  int t = threadIdx.x;
  int w = t >> 6, lane = t & 63;
  int m = lane & 15, q = lane >> 4;
  int row0 = blockIdx.x * 128;
  floatx4 acc[NCT];
  #pragma unroll
  for (int ct = 0; ct < NCT; ct++) acc[ct] = (floatx4)0.f;

  for (int kc = 0; kc < 4; kc++){
    int k0 = kc * 32;
    __syncthreads();
    {
      int r = t >> 2, kq = t & 3;
      int gr = row0 + r;
      int grc = (gr < nrows) ? gr : 0;
      *(uint4*)(Xs + r * KST + kq * 8) = *(const uint4*)(X + (size_t)grc * NCH + k0 + kq * 8);
    }
    #pragma unroll
    for (int i = t; i < NCT * 16 * 4; i += 512){
      int n = i >> 2, kq = i & 3;
      const short* sh = (n < 128) ? (Whi0 + n * NCH) : (Whi1 + (n - 128) * NCH);
      const short* sl = (n < 128) ? (Wlo0 + n * NCH) : (Wlo1 + (n - 128) * NCH);
      *(uint4*)(Whs + n * KST + kq * 8) = *(const uint4*)(sh + k0 + kq * 8);
      *(uint4*)(Wls + n * KST + kq * 8) = *(const uint4*)(sl + k0 + kq * 8);
    }
    __syncthreads();
    half8 a = *(const half8*)(Xs + (w * 16 + m) * KST + q * 8);
    #pragma unroll
    for (int ct = 0; ct < NCT; ct++){
      half8 bh = *(const half8*)(Whs + (ct * 16 + m) * KST + q * 8);
      half8 bl = *(const half8*)(Wls + (ct * 16 + m) * KST + q * 8);
      acc[ct] = __builtin_amdgcn_mfma_f32_16x16x32_f16(a, bh, acc[ct], 0, 0, 0);
      acc[ct] = __builtin_amdgcn_mfma_f32_16x16x32_f16(a, bl, acc[ct], 0, 0, 0);
    }
  }
  #pragma unroll
  for (int r = 0; r < 4; r++){
    int grow = row0 + w * 16 + q * 4 + r;
    if (grow < nrows){
      float sc = do_scale ? scale[grow] : 1.0f;
      #pragma unroll
      for (int ct = 0; ct < NCT; ct++){
        __half val = __float2half(acc[ct][r] * sc);
        if (ct < 8) O0[(size_t)grow * NCH + ct * 16 + m] = val;
        else        O1[(size_t)grow * NCH + (ct - 8) * 16 + m] = val;
      }
    }
  }
}

// ---------------- GCN aggregation: wave per node, 16B/lane gathers ----------------
// edge_dinv=1: s unscaled, gather dinv[r] per edge (agg1, fused-gemm constraint).
// edge_dinv=0: s pre-scaled by dinv (agg2 fast path, r6-style plain adds).
__global__ __launch_bounds__(256) void agg_kernel(
    const __half* __restrict__ s, const float* __restrict__ dinv,
    const int* __restrict__ offs, const int* __restrict__ counts,
    const int* __restrict__ rows_sorted, const float* __restrict__ bias,
    __half* __restrict__ outp, int N, int do_relu, int edge_dinv){
  int wave = (int)((blockIdx.x * blockDim.x + threadIdx.x) >> 6);
  int lane = threadIdx.x & 63;
  if (wave >= N) return;
  int c = wave;
  int g = lane >> 4, h = lane & 15;
  float di = dinv[c];
  float wself = edge_dinv ? di : 1.0f;
  float acc[8] = {0.f,0.f,0.f,0.f,0.f,0.f,0.f,0.f};
  if (g == 0){
    uint4 v = *(const uint4*)(s + (size_t)c * NCH + h * 8);
    const __half2* hp = (const __half2*)&v;
    #pragma unroll
    for (int i = 0; i < 4; i++){
      float2 f = __half22float2(hp[i]);
      acc[2*i] = fmaf(wself, f.x, acc[2*i]); acc[2*i+1] = fmaf(wself, f.y, acc[2*i+1]);
    }
  }
  int off = offs[c], cnt = counts[c];
  for (int chunk = 0; chunk < cnt; chunk += 64){
    int nn = min(64, cnt - chunk);
    int myidx = (lane < nn) ? rows_sorted[off + chunk + lane] : 0;
    float mydinv = 1.0f;
    if (edge_dinv && lane < nn) mydinv = dinv[myidx];
    int jmax = (nn + 3) >> 2;
    #pragma unroll 4
    for (int j = 0; j < jmax; j++){
      int e = 4 * j + g;
      int r  = __shfl(myidx, e & 63, 64);
      float dr = edge_dinv ? __shfl(mydinv, e & 63, 64) : 1.0f;
      if (e < nn){
        uint4 v = *(const uint4*)(s + (size_t)r * NCH + h * 8);
        const __half2* hp = (const __half2*)&v;
        #pragma unroll
        for (int i = 0; i < 4; i++){
          float2 f = __half22float2(hp[i]);
          acc[2*i] = fmaf(dr, f.x, acc[2*i]); acc[2*i+1] = fmaf(dr, f.y, acc[2*i+1]);
        }
      }
    }
  }
  #pragma unroll
  for (int i = 0; i < 8; i++){
    acc[i] += __shfl_xor(acc[i], 16, 64);
    acc[i] += __shfl_xor(acc[i], 32, 64);
  }
  if (g == 0){
    float4 b0 = *(const float4*)(bias + h * 8);
    float4 b1 = *(const float4*)(bias + h * 8 + 4);
    float o[8];
    o[0] = di*acc[0]+b0.x; o[1] = di*acc[1]+b0.y; o[2] = di*acc[2]+b0.z; o[3] = di*acc[3]+b0.w;
    o[4] = di*acc[4]+b1.x; o[5] = di*acc[5]+b1.y; o[6] = di*acc[6]+b1.z; o[7] = di*acc[7]+b1.w;
    if (do_relu){
      #pragma unroll
      for (int i = 0; i < 8; i++) o[i] = fmaxf(o[i], 0.f);
    }
    __half2 packed[4];
    #pragma unroll
    for (int i = 0; i < 4; i++) packed[i] = __floats2half2_rn(o[2*i], o[2*i+1]);
    *(uint4*)(outp + (size_t)c * NCH + h * 8) = *(uint4*)packed;
  }
}

// ---------------- Pair head: wave per 4 pairs (8 gathers in flight), 16B/lane ----------------
__global__ __launch_bounds__(256) void pair_kernel(
    const __half* __restrict__ A, const __half* __restrict__ B,
    const int* __restrict__ src, const int* __restrict__ dst,
    const float* __restrict__ bm1, const float* __restrict__ Wm2,
    const float* __restrict__ bm2, float* __restrict__ outp, int P){
  int gwave = (int)((blockIdx.x * blockDim.x + threadIdx.x) >> 6);
  int lane  = threadIdx.x & 63;
  int nw    = (int)((gridDim.x * blockDim.x) >> 6);
  int g = lane >> 4, h = lane & 15;
  float bb[8], ww[8];
  {
    float4 t0 = *(const float4*)(bm1 + h * 8);
    float4 t1 = *(const float4*)(bm1 + h * 8 + 4);
    bb[0]=t0.x; bb[1]=t0.y; bb[2]=t0.z; bb[3]=t0.w;
    bb[4]=t1.x; bb[5]=t1.y; bb[6]=t1.z; bb[7]=t1.w;
    float4 w0 = *(const float4*)(Wm2 + h * 8);
    float4 w1 = *(const float4*)(Wm2 + h * 8 + 4);
    ww[0]=w0.x; ww[1]=w0.y; ww[2]=w0.z; ww[3]=w0.w;
    ww[4]=w1.x; ww[5]=w1.y; ww[6]=w1.z; ww[7]=w1.w;
  }
  float bsc = bm2[0];
  const __half* basep = (g & 1) ? B : A;
  const int* idxp = (g & 1) ? dst : src;
  for (int p0 = gwave * 4; p0 < P; p0 += nw * 4){
    int piA = p0 + (g >> 1);
    int piB = p0 + 2 + (g >> 1);
    int piAX = (piA < P) ? piA : P - 1;
    int piBX = (piB < P) ? piB : P - 1;
    int nodeA = idxp[piAX];
    int nodeB = idxp[piBX];
    uint4 vA = *(const uint4*)(basep + (size_t)nodeA * NCH + h * 8);
    uint4 vB = *(const uint4*)(basep + (size_t)nodeB * NCH + h * 8);
    const __half2* hpA = (const __half2*)&vA;
    const __half2* hpB = (const __half2*)&vB;
    float fA[8], fB[8];
    #pragma unroll
    for (int i = 0; i < 4; i++){
      float2 ta = __half22float2(hpA[i]);
      float2 tb = __half22float2(hpB[i]);
      fA[2*i] = ta.x; fA[2*i+1] = ta.y;
      fB[2*i] = tb.x; fB[2*i+1] = tb.y;
    }
    float pA = 0.f, pB = 0.f;
    #pragma unroll
    for (int i = 0; i < 8; i++){
      float oA = __shfl_xor(fA[i], 16, 64);
      float oB = __shfl_xor(fB[i], 16, 64);
      float zA = fmaxf(fA[i] + oA + bb[i], 0.f);
      float zB = fmaxf(fB[i] + oB + bb[i], 0.f);
      pA += zA * ww[i];
      pB += zB * ww[i];
    }
    #pragma unroll
    for (int d = 1; d <= 8; d <<= 1){
      pA += __shfl_xor(pA, d, 64);
      pB += __shfl_xor(pB, d, 64);
    }
    if ((lane & 31) == 0){
      if (piA < P) outp[piA] = pA + bsc;
      if (piB < P) outp[piB] = pB + bsc;
    }
  }
}

// ---------------- launch ----------------

extern "C" void kernel_launch(void* const* d_in, const int* in_sizes, int n_in,
                              void* d_out, int out_size, void* d_ws, size_t ws_size,
                              hipStream_t stream){
  const float* x   = (const float*)d_in[0];
  const int*   ei  = (const int*)  d_in[1];
  const int*   ep  = (const int*)  d_in[2];
  const float* W1  = (const float*)d_in[3];
  const float* b1  = (const float*)d_in[4];
  const float* W2  = (const float*)d_in[5];
  const float* b2  = (const float*)d_in[6];
  const float* Wm1 = (const float*)d_in[7];
  const float* bm1 = (const float*)d_in[8];
  const float* Wm2 = (const float*)d_in[9];
  const float* bm2 = (const float*)d_in[10];
  float* outp = (float*)d_out;

  const int N = in_sizes[0] / NCH;
  const int E = in_sizes[1] / 2;
  const int P = in_sizes[2] / 2;
  const int NB = (N + G_NODES - 1) / G_NODES;

  char* base = (char*)d_ws;
  size_t off = 0;
  int*      counts      = (int*)     (base + off); off = align256(off + (size_t)N * 4);
  int*      offs        = (int*)     (base + off); off = align256(off + (size_t)N * 4);
  float*    dinv        = (float*)   (base + off); off = align256(off + (size_t)N * 4);
  int*      gcur        = (int*)     (base + off); off = align256(off + (size_t)NB * 4);
  unsigned* bucketed    = (unsigned*)(base + off); off = align256(off + (size_t)NB * RCAP * 4);
  int*      rows_sorted = (int*)     (base + off); off = align256(off + (size_t)NB * RCAP * 4);
  short*    planes      = (short*)   (base + off); off = align256(off + (size_t)8 * 16384 * 2);
  __half*   s1buf       = (__half*)  (base + off); off = align256(off + (size_t)N * NCH * 2);
  __half*   h1buf       = (__half*)  (base + off); off = align256(off + (size_t)N * NCH * 2);
  __half*   s2buf       = (__half*)  (base + off); off = align256(off + (size_t)N * NCH * 2);
  __half*   sA          = (__half*)  (base + off); off = align256(off + (size_t)N * NCH * 2);
  __half*   sB          = (__half*)  (base + off); off = align256(off + (size_t)N * NCH * 2);
  (void)ws_size; (void)n_in; (void)out_size;

  short* W1hi = planes + 0 * 16384;
  short* W1lo = planes + 1 * 16384;
  short* W2hi = planes + 2 * 16384;
  short* W2lo = planes + 3 * 16384;
  short* Wahi = planes + 4 * 16384;
  short* Walo = planes + 5 * 16384;
  short* Wbhi = planes + 6 * 16384;
  short* Wblo = planes + 7 * 16384;

  const int* row = ei;       // edge_index[0] = source
  const int* col = ei + E;   // edge_index[1] = target
  const int* psrc = ep;
  const int* pdst = ep + P;

  int gemm_grid = (N + 127) / 128;
  int agg_grid  = (N + 3) / 4;

  // 0: zero bucket cursors (cheap graph memset node)
  hipMemsetAsync(gcur, 0, (size_t)NB * 4, stream);
  // 1: edge bucketing + W-plane prep tail
  binA_kernel<<<(E + EPB - 1) / EPB, 256, 0, stream>>>(row, col, gcur, bucketed, E, NB,
                                                       W1, W2, Wm1, planes);
  // 2: fused conv1 GEMM (t1 = x@W1, UNscaled) || CSR finalize (no shared data -> no race)
  fused_gemm_binB<<<gemm_grid + NB, 512, 0, stream>>>(
      x, W1hi, W1lo, s1buf, N, gemm_grid,
      bucketed, gcur, rows_sorted, offs, counts, dinv, N);
  // 3: conv1 agg (edge-dinv path): h1 = relu(dinv*(dinv*t1[c]+sum dinv[r]t1[r])+b1)
  agg_kernel<<<agg_grid, 256, 0, stream>>>(s1buf, dinv, offs, counts, rows_sorted, b1, h1buf, N, 1, 1);
  // 4: conv2 transform, pre-scaled: s2 = dinv*(h1@W2)  (dinv ready -> no race)
  gemm_f16k<8><<<gemm_grid, 512, 0, stream>>>(h1buf, W2hi, W2lo, W2hi, W2lo, dinv, 1, s2buf, s2buf, N);
  // 5: conv2 agg (fast path, plain adds): h2 = dinv*(s2[c]+sum s2[r])+b2
  agg_kernel<<<agg_grid, 256, 0, stream>>>(s2buf, dinv, offs, counts, rows_sorted, b2, h1buf, N, 0, 0);
  // 6: pair precompute (dual): sA = h2@Wm1a, sB = h2@Wm1b
  gemm_f16k<16><<<gemm_grid, 512, 0, stream>>>(h1buf, Wahi, Walo, Wbhi, Wblo, dinv, 0, sA, sB, N);
  // 7: out[p] = relu(A[src]+B[dst]+bm1)@Wm2 + bm2
  pair_kernel<<<8192, 256, 0, stream>>>(sA, sB, psrc, pdst, bm1, Wm2, bm2, outp, P);
}